// Round 3
// baseline (437.203 us; speedup 1.0000x reference)
//
#include <hip/hip_runtime.h>
#include <hip/hip_bf16.h>

#define N_NODES 100000
#define N_EDGES 1600000
#define N_EL    200000
// D_IN = D_HID = 128; layer-3 output D = 64. f32 inputs, int32 indices, f32 output.
// Round 18:
//  (1) rank: 8 edges/thread (8 independent atomics in flight) -> latency hidden
//      by MLP instead of occupancy; 782 rank blocks interleaved 2:1 with gemm.
//      launch_bounds(256,5): LDS allows 5 blocks/CU (was capped at 4).
//  (2) scan1+2+3 fused into k_scanF (last-block pattern, device-scope atomics);
//      gathers/fill compute rowptr = lrp[i] + boff[i>>9] on the fly.
//  (3) new prescale pass (t *= dinv[row], merged into fill kernel's grid):
//      all gathers become unweighted; dinv[src] random-gather eliminated;
//      pad row t[N_NODES] zeroed by the same pass.
//  Dispatches: 13 -> 10.

#define CPAD 16                            // ints per counter line
#define GT_GEMM ((N_NODES + 63) / 64)      // 1563 gemm blocks (64 rows each)
#define GR_RANK 782                        // rank blocks (2048 edges each)
#define GRID_FAT (3 * GR_RANK)             // 2346 (2:1 gemm:rank interleave)
#define NB2 ((N_NODES + 511) / 512)        // 196 scan blocks
#define GF_FILL ((N_EDGES + 255) / 256)    // 6250 fill blocks
#define GF_PRE  ((N_NODES + 1 + 3) / 4)    // 25001 prescale blocks (4 nodes each)

typedef unsigned int uint32;
typedef unsigned short ushort16;
typedef __attribute__((ext_vector_type(8))) short short8;   // 8 bf16 (4 VGPRs)
typedef __attribute__((ext_vector_type(4))) float f32x4;

static __device__ __forceinline__ ushort16 f2bf(float f) {
    uint32 u = __float_as_uint(f);
    u += 0x7fffu + ((u >> 16) & 1u);      // RNE
    return (ushort16)(u >> 16);
}
static __device__ __forceinline__ float bf_lo(uint32 p) { return __uint_as_float(p << 16); }
static __device__ __forceinline__ float bf_hi(uint32 p) { return __uint_as_float(p & 0xffff0000u); }
static __device__ __forceinline__ float bf2f(ushort16 h) { return __uint_as_float((uint32)h << 16); }

// ---------------- fused scan: local scan + dinv; last block scans block sums ----
__global__ void k_scanF(const int* __restrict__ cpad, int* __restrict__ lrp,
                        float* __restrict__ dinv, int* __restrict__ bsum,
                        int* __restrict__ boff, int* __restrict__ cnt) {
    __shared__ int s[512];
    __shared__ int lastflag;
    int t = threadIdx.x;
    int i = blockIdx.x * 512 + t;
    int v = (i < N_NODES) ? cpad[(size_t)i * CPAD] : 0;
    if (i < N_NODES) dinv[i] = 1.0f / sqrtf((float)(v + 1));   // +1 self-loop
    s[t] = v;
    __syncthreads();
    for (int off = 1; off < 512; off <<= 1) {
        int u = (t >= off) ? s[t - off] : 0;
        __syncthreads();
        s[t] += u;
        __syncthreads();
    }
    if (i <= N_NODES) lrp[i] = s[t] - v;            // local exclusive scan
    if (t == 0) {
        __hip_atomic_store(&bsum[blockIdx.x], s[511], __ATOMIC_RELEASE,
                           __HIP_MEMORY_SCOPE_AGENT);
        int c = __hip_atomic_fetch_add(cnt, 1, __ATOMIC_ACQ_REL,
                                       __HIP_MEMORY_SCOPE_AGENT);
        lastflag = (c == NB2 - 1);
    }
    __syncthreads();
    if (!lastflag) return;
    // last arriving block: exclusive scan of the 196 block sums
    int bv = (t < NB2) ? __hip_atomic_load(&bsum[t], __ATOMIC_ACQUIRE,
                                           __HIP_MEMORY_SCOPE_AGENT) : 0;
    s[t] = bv;
    __syncthreads();
    for (int off = 1; off < 512; off <<= 1) {
        int u = (t >= off) ? s[t - off] : 0;
        __syncthreads();
        s[t] += u;
        __syncthreads();
    }
    if (t < NB2) boff[t] = s[t] - bv;
}

// ---------------- fill (atomic-free) + prescale t by dinv + zero pad row --------
__global__ void k_fill2p(const int* __restrict__ src, const int* __restrict__ dst,
                         const int* __restrict__ lrp, const int* __restrict__ boff,
                         const int* __restrict__ r, int* __restrict__ col,
                         const float* __restrict__ dinv, uint32* __restrict__ t32) {
    unsigned bid = blockIdx.x;
    int tid = threadIdx.x;
    if (bid < GF_FILL) {
        int e = bid * 256 + tid;
        if (e >= N_EDGES) return;
        int dd = dst[e];
        int pos = lrp[dd] + boff[dd >> 9] + r[e];
        __builtin_nontemporal_store(src[e], &col[pos]);
    } else {
        int node = (bid - GF_FILL) * 4 + (tid >> 6);
        int lane = tid & 63;
        if (node > N_NODES) return;
        float di = (node < N_NODES) ? dinv[node] : 0.f;   // pad row -> zeros
        size_t idx = (size_t)node * 64 + lane;
        uint32 p = t32[idx];
        float lo = bf_lo(p) * di, hi = bf_hi(p) * di;
        t32[idx] = (uint32)f2bf(lo) | ((uint32)f2bf(hi) << 16);
    }
}

// ---------------- A-fragment loaders ----------------
static __device__ __forceinline__ short8 load_afrag(const float* arow, int off) {
    float4 a0 = *(const float4*)(arow + off);
    float4 a1 = *(const float4*)(arow + off + 4);
    short8 af;
    af[0] = (short)f2bf(a0.x); af[1] = (short)f2bf(a0.y);
    af[2] = (short)f2bf(a0.z); af[3] = (short)f2bf(a0.w);
    af[4] = (short)f2bf(a1.x); af[5] = (short)f2bf(a1.y);
    af[6] = (short)f2bf(a1.z); af[7] = (short)f2bf(a1.w);
    return af;
}
static __device__ __forceinline__ short8 load_afrag(const ushort16* arow, int off) {
    return *(const short8*)(arow + off);   // 16B aligned
}

// ---- MFMA GEMM body: t[n,0:D] = bf16( [dinv[n]] * (A[n,:128] @ W[128,D]) ) ----
template <int D, typename AT, bool SCALE, int OS>
static __device__ __forceinline__ void gemm_body(int bid, const AT* __restrict__ A,
        const float* __restrict__ W, const float* __restrict__ dinv,
        ushort16* __restrict__ C) {
    constexpr int NT = D / 16;                 // 8 (D=128) or 4 (D=64)
    constexpr int LNT = (NT == 8) ? 3 : 2;
    __shared__ short sB[4 * NT * 64 * 8];      // 32 KB / 16 KB

    int tid = threadIdx.x;

    // stage W -> LDS in B-fragment order; 8 consecutive shorts per thread ->
    // ds_write_b128, consecutive lanes -> consecutive 16B -> conflict-free.
    constexpr int COMBOS = 4 * 4 * NT * 16;    // 2048 / 1024
    for (int cc = tid; cc < COMBOS; cc += 256) {
        int nn = cc & 15;
        int nt = (cc >> 4) & (NT - 1);
        int q  = (cc >> (4 + LNT)) & 3;
        int kt = cc >> (6 + LNT);
        short8 pk;
#pragma unroll
        for (int j = 0; j < 8; ++j)
            pk[j] = (short)f2bf(W[(kt * 32 + q * 8 + j) * D + nt * 16 + nn]);
        *(short8*)&sB[(((kt * NT + nt) * 64) + q * 16 + nn) * 8] = pk;
    }
    __syncthreads();

    int w = tid >> 6;
    int l = tid & 63;
    int q = l >> 4;
    int nn15 = l & 15;
    int m0 = bid * 64 + w * 16;

    f32x4 acc[NT];
#pragma unroll
    for (int i = 0; i < NT; ++i) acc[i] = (f32x4){0.f, 0.f, 0.f, 0.f};

    int m = m0 + nn15;
    m = min(m, N_NODES - 1);                    // tail clamp (loads only)
    const AT* arow = A + (size_t)m * 128;

#pragma unroll
    for (int kt = 0; kt < 4; ++kt) {
        short8 af = load_afrag(arow, kt * 32 + q * 8);
#pragma unroll
        for (int nt = 0; nt < NT; ++nt) {
            short8 bf = *(const short8*)&sB[((kt * NT + nt) * 64 + l) * 8];
            acc[nt] = __builtin_amdgcn_mfma_f32_16x16x32_bf16(af, bf, acc[nt], 0, 0, 0);
        }
    }

    // epilogue: node = m0 + q*4 + r, col = nt*16 + nn15
    float4 dv;
    if constexpr (SCALE) dv = *(const float4*)(dinv + m0 + 4 * q);
    const float* dvp = (const float*)&dv;
#pragma unroll
    for (int nt = 0; nt < NT; ++nt) {
#pragma unroll
        for (int r = 0; r < 4; ++r) {
            int node = m0 + q * 4 + r;
            if (node < N_NODES) {
                float val = acc[nt][r];
                if constexpr (SCALE) val *= dvp[r];
                C[(size_t)node * OS + nt * 16 + nn15] = f2bf(val);
            }
        }
    }
}

template <int D, typename AT, bool SCALE, int OS>
__global__ __launch_bounds__(256, 5) void k_gemm_mfma(const AT* __restrict__ A,
        const float* __restrict__ W, const float* __restrict__ dinv,
        ushort16* __restrict__ C) {
    gemm_body<D, AT, SCALE, OS>(blockIdx.x, A, W, dinv, C);
}

// ------- fat kernel: GEMM1 + rank (8 edges/thread), 2:1 interleaved -------------
__global__ __launch_bounds__(256, 5) void k_fat1(const float* __restrict__ A,
        const float* __restrict__ W, ushort16* __restrict__ C,
        const int* __restrict__ dst, int* __restrict__ cpad, int* __restrict__ r) {
    unsigned bid = blockIdx.x;
    unsigned g = bid / 3u;
    unsigned rem = bid - g * 3u;
    if (rem < 2u) {                             // gemm role
        unsigned gid = g * 2u + rem;
        if (gid < GT_GEMM)
            gemm_body<128, float, false, 128>(gid, A, W, nullptr, C);
    } else {                                    // rank role: 2048 edges/block
        unsigned e0 = g * 2048u + threadIdx.x;
        int d[8], rr[8];
#pragma unroll
        for (int k = 0; k < 8; ++k) {
            unsigned e = e0 + k * 256u;
            if (e < N_EDGES) d[k] = dst[e];
        }
#pragma unroll
        for (int k = 0; k < 8; ++k) {           // 8 independent atomics in flight
            unsigned e = e0 + k * 256u;
            if (e < N_EDGES) rr[k] = atomicAdd(&cpad[(size_t)d[k] * CPAD], 1);
        }
#pragma unroll
        for (int k = 0; k < 8; ++k) {
            unsigned e = e0 + k * 256u;
            if (e < N_EDGES) __builtin_nontemporal_store(rr[k], &r[e]);
        }
    }
}

// ---------------- gather, D=128: one wave/node, bulk-col + LDS broadcast --------
// t prescaled by dinv[src]; pads -> zero row t[N_NODES].
template <bool RELU>
__global__ void k_gather128(const int* __restrict__ lrp, const int* __restrict__ boff,
                            const int* __restrict__ col, const float* __restrict__ dinv,
                            const uint32* __restrict__ t, const float* __restrict__ b,
                            uint32* __restrict__ outbuf) {
    __shared__ int sc[4][64];
    int tid = threadIdx.x;
    unsigned wid = (blockIdx.x * 256u + tid) >> 6;
    if (wid >= N_NODES) return;
    int w = tid >> 6;
    int lane = tid & 63;
    int beg = lrp[wid] + boff[wid >> 9];
    int end = lrp[wid + 1] + boff[(wid + 1) >> 9];
    float di = dinv[wid];
    uint32 p = t[(size_t)wid * 64 + lane];
    float ax = bf_lo(p), ay = bf_hi(p);                  // self-loop (prescaled)
    for (int base = beg; base < end; base += 64) {
        int cnt = min(end - base, 64);
        int c = N_NODES;
        if (lane < cnt) c = col[base + lane];            // 1 coalesced load / 64 edges
        sc[w][lane] = c;
        int nb = (cnt + 7) >> 3;                          // padded 8-batches
        for (int j8 = 0; j8 < nb; ++j8) {
            int j = j8 << 3;
            int s0 = sc[w][j+0], s1 = sc[w][j+1], s2 = sc[w][j+2], s3 = sc[w][j+3];
            int s4 = sc[w][j+4], s5 = sc[w][j+5], s6 = sc[w][j+6], s7 = sc[w][j+7];
            uint32 v0 = t[(size_t)s0 * 64 + lane];
            uint32 v1 = t[(size_t)s1 * 64 + lane];
            uint32 v2 = t[(size_t)s2 * 64 + lane];
            uint32 v3 = t[(size_t)s3 * 64 + lane];
            uint32 v4 = t[(size_t)s4 * 64 + lane];
            uint32 v5 = t[(size_t)s5 * 64 + lane];
            uint32 v6 = t[(size_t)s6 * 64 + lane];
            uint32 v7 = t[(size_t)s7 * 64 + lane];
            ax += (bf_lo(v0) + bf_lo(v1)) + (bf_lo(v2) + bf_lo(v3))
                + ((bf_lo(v4) + bf_lo(v5)) + (bf_lo(v6) + bf_lo(v7)));
            ay += (bf_hi(v0) + bf_hi(v1)) + (bf_hi(v2) + bf_hi(v3))
                + ((bf_hi(v4) + bf_hi(v5)) + (bf_hi(v6) + bf_hi(v7)));
        }
    }
    float2 bb = ((const float2*)b)[lane];
    float ox = di * ax + bb.x;
    float oy = di * ay + bb.y;
    if (RELU) { ox = fmaxf(ox, 0.f); oy = fmaxf(oy, 0.f); }
    __builtin_nontemporal_store((uint32)f2bf(ox) | ((uint32)f2bf(oy) << 16),
                                &outbuf[(size_t)wid * 64 + lane]);
}

// ---- gather, D=64: t prescaled, row stride 128 shorts; pads -> zero row --------
template <bool RELU>
__global__ void k_gather64(const int* __restrict__ lrp, const int* __restrict__ boff,
                           const int* __restrict__ col, const float* __restrict__ dinv,
                           const ushort16* __restrict__ t, const float* __restrict__ b,
                           ushort16* __restrict__ outbuf) {
    __shared__ int sc[4][64];
    int tid = threadIdx.x;
    unsigned wid = (blockIdx.x * 256u + tid) >> 6;
    if (wid >= N_NODES) return;
    int w = tid >> 6;
    int lane = tid & 63;
    int beg = lrp[wid] + boff[wid >> 9];
    int end = lrp[wid + 1] + boff[(wid + 1) >> 9];
    float di = dinv[wid];
    float acc = bf2f(t[(size_t)wid * 128 + lane]);   // self-loop (prescaled)
    for (int base = beg; base < end; base += 64) {
        int cnt = min(end - base, 64);
        int c = N_NODES;
        if (lane < cnt) c = col[base + lane];
        sc[w][lane] = c;
        int nb = (cnt + 7) >> 3;
        for (int j8 = 0; j8 < nb; ++j8) {
            int j = j8 << 3;
            int s0 = sc[w][j+0], s1 = sc[w][j+1], s2 = sc[w][j+2], s3 = sc[w][j+3];
            int s4 = sc[w][j+4], s5 = sc[w][j+5], s6 = sc[w][j+6], s7 = sc[w][j+7];
            float v0 = bf2f(t[(size_t)s0 * 128 + lane]);
            float v1 = bf2f(t[(size_t)s1 * 128 + lane]);
            float v2 = bf2f(t[(size_t)s2 * 128 + lane]);
            float v3 = bf2f(t[(size_t)s3 * 128 + lane]);
            float v4 = bf2f(t[(size_t)s4 * 128 + lane]);
            float v5 = bf2f(t[(size_t)s5 * 128 + lane]);
            float v6 = bf2f(t[(size_t)s6 * 128 + lane]);
            float v7 = bf2f(t[(size_t)s7 * 128 + lane]);
            acc += (v0 + v1) + (v2 + v3) + ((v4 + v5) + (v6 + v7));
        }
    }
    float o = di * acc + b[lane];
    if (RELU) o = fmaxf(o, 0.f);
    __builtin_nontemporal_store(f2bf(o), &outbuf[(size_t)wid * 64 + lane]);
}

// ---------------- decode: z is bf16 [N x 64] ----------------
__global__ void k_decode(const int* __restrict__ eli, const ushort16* __restrict__ z,
                         float* __restrict__ out) {
    int e = blockIdx.x * blockDim.x + threadIdx.x;
    if (e >= N_EL) return;
    int a = eli[e];
    int b = eli[N_EL + e];
    const uint4* za = (const uint4*)(z + (size_t)a * 64);
    const uint4* zb = (const uint4*)(z + (size_t)b * 64);
    float acc = 0.0f;
#pragma unroll
    for (int i = 0; i < 8; ++i) {
        uint4 va = za[i], vb = zb[i];
        acc += bf_lo(va.x) * bf_lo(vb.x) + bf_hi(va.x) * bf_hi(vb.x);
        acc += bf_lo(va.y) * bf_lo(vb.y) + bf_hi(va.y) * bf_hi(vb.y);
        acc += bf_lo(va.z) * bf_lo(vb.z) + bf_hi(va.z) * bf_hi(vb.z);
        acc += bf_lo(va.w) * bf_lo(vb.w) + bf_hi(va.w) * bf_hi(vb.w);
    }
    out[e] = acc;
}

extern "C" void kernel_launch(void* const* d_in, const int* in_sizes, int n_in,
                              void* d_out, int out_size, void* d_ws, size_t ws_size,
                              hipStream_t stream) {
    const float* x   = (const float*)d_in[0];
    const int*   ei  = (const int*)d_in[1];
    const int*   eli = (const int*)d_in[2];
    const float* W1  = (const float*)d_in[3];
    const float* b1  = (const float*)d_in[4];
    const float* W2  = (const float*)d_in[5];
    const float* b2  = (const float*)d_in[6];
    const float* W3  = (const float*)d_in[7];
    const float* b3  = (const float*)d_in[8];
    float* out = (float*)d_out;

    const int* srcA = ei;
    const int* dstA = ei + N_EDGES;

    // workspace layout (bytes) — non-overlapping:
    //   dinv [0, 400,000)   lrp [1M, +400K+4)
    //   bsum [1888K) boff [1896K)   col [2M, 8.4M)   r [9M, 15.4M)
    //   t    [16M, +25.6M+256)  bf16 N x 128 (+ zero pad row N_NODES)
    //   aggb [48M, +25.6M)  bf16 N x 128 (layers), N x 64 (final z)
    //   cpad [80M, +6.4M+64)  line-padded counters + scanF arrival counter
    char* ws = (char*)d_ws;
    float*    dinv   = (float*)   (ws + 0);
    int*      lrp    = (int*)     (ws + (1024u << 10));
    int*      bsum   = (int*)     (ws + (1888u << 10));
    int*      boff   = (int*)     (ws + (1896u << 10));
    int*      col    = (int*)     (ws + (2048u << 10));
    int*      r      = (int*)     (ws + (9u << 20));
    ushort16* t      = (ushort16*)(ws + (16u << 20));
    ushort16* aggb   = (ushort16*)(ws + (48u << 20));
    int*      cpad   = (int*)     (ws + (80u << 20));
    int*      cnt    = cpad + (size_t)N_NODES * CPAD;     // covered by memset

    const int B = 256;
    const int gG  = (N_NODES * 64 + B - 1) / B;
    const int gEL = (N_EL + B - 1) / B;

    // ---- CSR build overlapped with GEMM1 (interleaved block roles) ----
    hipMemsetAsync(cpad, 0, ((size_t)N_NODES * CPAD + 16) * sizeof(int), stream);
    k_fat1<<<GRID_FAT, B, 0, stream>>>(x, W1, t, dstA, cpad, r);
    k_scanF<<<NB2, 512, 0, stream>>>(cpad, lrp, dinv, bsum, boff, cnt);
    k_fill2p<<<GF_FILL + GF_PRE, B, 0, stream>>>(srcA, dstA, lrp, boff, r, col,
                                                 dinv, (uint32*)t);

    // ---- layer 1 aggregation (t prescaled by fill2p) ----
    k_gather128<true><<<gG, B, 0, stream>>>(lrp, boff, col, dinv, (const uint32*)t,
                                            b1, (uint32*)aggb);
    // ---- layer 2 (t prescaled by dinv in epilogue) ----
    k_gemm_mfma<128, ushort16, true, 128><<<GT_GEMM, B, 0, stream>>>(aggb, W2, dinv, t);
    k_gather128<true><<<gG, B, 0, stream>>>(lrp, boff, col, dinv, (const uint32*)t,
                                            b2, (uint32*)aggb);
    // ---- layer 3 (t prescaled, row stride 128 so pad row is shared) ----
    k_gemm_mfma<64, ushort16, true, 128><<<GT_GEMM, B, 0, stream>>>(aggb, W3, dinv, t);
    k_gather64<false><<<gG, B, 0, stream>>>(lrp, boff, col, dinv, t, b3, aggb);

    // ---- decode ----
    k_decode<<<gEL, B, 0, stream>>>(eli, aggb, out);
}